// Round 16
// baseline (101.986 us; speedup 1.0000x reference)
//
#include <hip/hip_runtime.h>

#define C_IN   64
#define HW_DIM 64
#define C_OUT  128
#define NG     8
#define BM     128      // pixels per block = TWO image rows
#define NSPL_STEPS 72   // spline K-steps of 64 (8 chan-groups x 9 taps)
#define NSTEPS 81
#define NHALF  36       // spline steps per K-half
#define NBASE  9
#define NPAD   66

// XE4[b][yp(66)][grp(8)][xp(66)][cg(8)][g(8)] bf16 ; strides (elems):
#define XE_XP   64
#define XE_GRP  4224      // 66*64
#define XE_YP   33792     // 8*4224
#define XE_B    2230272   // 66*33792
// SE4[b][yp(66)][xp(66)][c(64)] bf16
#define SE_XP   64
#define SE_YP   4224
#define SE_B    278784

// d_ws layout (bytes)
#define WT_BYTES 1327104                  // 81*8192*2
#define XE_OFF   WT_BYTES
#define XE_BYTES (XE_B * 8 * 2)           // 35,684,352
#define SE_OFF   (XE_OFF + XE_BYTES)

typedef __attribute__((ext_vector_type(8))) __bf16 bf16x8;
typedef __attribute__((ext_vector_type(4))) float  f32x4;

// --------------------------------------------------------------------------
// Weight prep (r15 K-order): wt3[step(81)][nq(4)][n(2)][ks(2)][lane(64)][8].
// Spline step s = grp*9 + j: granule q = ks*4+g4 -> channel c = grp*8+q,
// elem e -> grid g: k_orig = (c*9+j)*8+e. Base step j: q = channel-octet,
// elem e -> c = q*8+e: f_orig = c*9+j.
// --------------------------------------------------------------------------
__global__ __launch_bounds__(256)
void prep_wt(const float* __restrict__ sw, const float* __restrict__ bw,
             __bf16* __restrict__ wt3)
{
  const int bid  = blockIdx.x;
  const int t    = threadIdx.x;
  const int nq   = t >> 6;
  const int lane = t & 63;
  const int l15  = lane & 15;
  const int g4   = lane >> 4;
#pragma unroll
  for (int n = 0; n < 2; ++n)
#pragma unroll
    for (int ks = 0; ks < 2; ++ks) {
      const int co = nq * 32 + n * 16 + l15;
      const int q  = ks * 4 + g4;
      bf16x8 v;
      if (bid < NSPL_STEPS) {
        const int grp = bid / 9, j = bid - 9 * grp;
        const int c   = grp * 8 + q;
#pragma unroll
        for (int e = 0; e < 8; ++e)
          v[e] = (__bf16)sw[(size_t)((c * 9 + j) * 8 + e) * C_OUT + co];
      } else {
        const int j = bid - NSPL_STEPS;
#pragma unroll
        for (int e = 0; e < 8; ++e)
          v[e] = (__bf16)bw[(size_t)((q * 8 + e) * 9 + j) * C_OUT + co];
      }
      *(bf16x8*)(wt3 + (size_t)bid * 8192 + nq * 2048 + (n * 2 + ks) * 512
                 + lane * 8) = v;
    }
}

// --------------------------------------------------------------------------
// XE expansion (r15): one block per (b, yp, grp).
// --------------------------------------------------------------------------
__global__ __launch_bounds__(256)
void expand_xe(const float* __restrict__ x, const float* __restrict__ grid,
               __bf16* __restrict__ xe)
{
  __shared__ __align__(16) __bf16 buf[528 * 8];
  const int bid = blockIdx.x;           // 8*66*8 = 4224
  const int b   = bid / 528;
  const int r   = bid - b * 528;
  const int yp  = r >> 3;
  const int grp = r & 7;
  const int t   = threadIdx.x;

  float gv[NG];
#pragma unroll
  for (int g = 0; g < NG; ++g) gv[g] = grid[g];

  for (int i = t; i < 528; i += 256) {  // i = xp*8 + cg
    const int xp = i >> 3;
    const int cg = i & 7;
    const int c  = grp * 8 + cg;
    float p = 0.f;
    if (xp >= 1 && xp <= HW_DIM && yp >= 1 && yp <= HW_DIM)
      p = x[(size_t)(b * C_IN + c) * (HW_DIM * HW_DIM)
            + (yp - 1) * HW_DIM + (xp - 1)];
    bf16x8 v;
#pragma unroll
    for (int g = 0; g < NG; ++g) {
      const float z = 1.75f * (p - gv[g]);
      v[g] = (__bf16)__expf(-z * z);
    }
    *(bf16x8*)(buf + i * 8) = v;
  }
  __syncthreads();
  __bf16* dst = xe + (size_t)b * XE_B + yp * XE_YP + grp * XE_GRP;
  for (int i = t; i < 528; i += 256)
    *(bf16x8*)(dst + i * 8) = *(const bf16x8*)(buf + i * 8);
}

// --------------------------------------------------------------------------
// SE expansion (r15): one block per (b, yp).
// --------------------------------------------------------------------------
__global__ __launch_bounds__(256)
void expand_se(const float* __restrict__ x, __bf16* __restrict__ se)
{
  __shared__ __align__(16) __bf16 buf[4224];
  const int bid = blockIdx.x;           // 8*66 = 528
  const int b   = bid / 66;
  const int yp  = bid - b * 66;
  const int t   = threadIdx.x;

  for (int i = t; i < 4224; i += 256) { // i = xp*64 + c
    const int xp = i >> 6;
    const int c  = i & 63;
    float p = 0.f;
    if (xp >= 1 && xp <= HW_DIM && yp >= 1 && yp <= HW_DIM)
      p = x[(size_t)(b * C_IN + c) * (HW_DIM * HW_DIM)
            + (yp - 1) * HW_DIM + (xp - 1)];
    const float e = __expf(-p);
    buf[i] = (__bf16)(p * __builtin_amdgcn_rcpf(1.f + e));
  }
  __syncthreads();
  __bf16* dst = se + (size_t)b * SE_B + yp * SE_YP;
  for (int i = t; i < 528; i += 256)
    *(bf16x8*)(dst + i * 8) = *(const bf16x8*)(buf + i * 8);
}

// --------------------------------------------------------------------------
// Output init: out[b][co][pix] = base_b[co]  (gemm halves atomic-add)
// --------------------------------------------------------------------------
__global__ __launch_bounds__(256)
void init_out(const float* __restrict__ bb, float* __restrict__ out)
{
  const int i4 = blockIdx.x * 256 + threadIdx.x;   // 1,048,576 threads
  const int e  = i4 * 4;
  const float v = bb[(e >> 12) & 127];
  *(f32x4*)(out + e) = f32x4{v, v, v, v};
}

static __device__ __forceinline__ void gload16(const __bf16* g, __bf16* l) {
  __builtin_amdgcn_global_load_lds(
      (const __attribute__((address_space(1))) void*)g,
      (__attribute__((address_space(3))) void*)l, 16, 0, 0);
}

// counted-vmcnt barrier (T4): keep 6 newest VMEM ops in flight across it
#define WAITBAR6() do {                                      \
    asm volatile("s_waitcnt vmcnt(6)" ::: "memory");         \
    __builtin_amdgcn_s_barrier();                            \
    __builtin_amdgcn_sched_barrier(0);                       \
  } while (0)

// --------------------------------------------------------------------------
// GEMM, BM=128 + split-K2: 512 blocks = 256 row-pair-blocks x 2 K-halves,
// 512 threads = 8 waves of 64px x 32co (mh = px-half, nq = co-quarter).
// B-tile L2 bytes halved vs r15 (128px amortize; mh-pair waves dedup in L1).
// Spline: 36 steps/half, distance-2 LDS ring, 6 VMEM ops/thread/step
// (2 gload_lds + 4 b128), vmcnt(6) barriers -- r15 schedule verbatim.
// K-half 1 adds 9 base steps. Epilogue: unsafeAtomicAdd onto bias-init out.
// --------------------------------------------------------------------------
__global__ __launch_bounds__(512, 4)
void kan_gemm(const __bf16* __restrict__ xe, const __bf16* __restrict__ se,
              const __bf16* __restrict__ wt3, float* __restrict__ out)
{
  __shared__ __align__(16) __bf16 As[3][BM][64];   // 3 x 16 KB ring

  const int t    = threadIdx.x;
  const int lane = t & 63;
  const int wid  = t >> 6;              // 0..7
  const int l15  = lane & 15;
  const int g4   = lane >> 4;
  const int mh   = wid >> 2;            // px half (rows y0 / y0+1)
  const int nq   = wid & 3;             // co quarter

  // bijective XCD swizzle: 512 blocks = 8 XCDs x 64
  const int bid = blockIdx.x;
  const int swz = (bid & 7) * 64 + (bid >> 3);
  const int kh  = swz & 1;              // K-half
  const int rb  = swz >> 1;             // row-pair block 0..255
  const int b   = rb >> 5;              // image
  const int y0  = (rb & 31) * 2;        // first image row (even)
  const int S0  = kh * NHALF;

  // A-staging: pass p slot = p*512+t -> px = p*64 + (t>>3), gslot = t&7;
  // slot holds feature-granule q = gslot ^ (px&7)  (px&7 same both passes).
  const int px0 = t >> 3;               // 0..63
  const int qs  = (t & 7) ^ (px0 & 7);

  f32x4 acc[2][4];
#pragma unroll
  for (int n = 0; n < 2; ++n)
#pragma unroll
    for (int m = 0; m < 4; ++m)
      acc[n][m] = f32x4{0.f, 0.f, 0.f, 0.f};

  const __bf16* xeb = xe + (size_t)b * XE_B + y0 * XE_YP;

  auto stageA = [&](int buf, int s) {
    const int grp = s / 9, j = s - 9 * grp;
    const int kt = j / 3, kw = j - 3 * kt;
    const __bf16* src = xeb + kt * XE_YP + grp * XE_GRP + kw * XE_XP
                      + px0 * 64 + qs * 8;
    __bf16* dst = &As[buf][0][0] + t * 8;
    gload16(src,         dst);           // rows y0+kt   (px 0..63)
    gload16(src + XE_YP, dst + 4096);    // rows y0+1+kt (px 64..127)
  };

  auto loadB = [&](bf16x8 (&wf)[2][2], int step) {
    const __bf16* wb = wt3 + (size_t)step * 8192 + nq * 2048 + lane * 8;
#pragma unroll
    for (int n = 0; n < 2; ++n)
#pragma unroll
      for (int ks = 0; ks < 2; ++ks)
        wf[n][ks] = *(const bf16x8*)(wb + (n * 2 + ks) * 512);
  };

  auto compute = [&](int buf, bf16x8 (&wf)[2][2]) {
    bf16x8 xf[4][2];
#pragma unroll
    for (int ks = 0; ks < 2; ++ks)
#pragma unroll
      for (int m = 0; m < 4; ++m) {
        const int pr = mh * 64 + m * 16 + l15;
        xf[m][ks] = *(const bf16x8*)(&As[buf][pr][(((ks * 4 + g4) ^ (pr & 7)) * 8)]);
      }
#pragma unroll
    for (int ks = 0; ks < 2; ++ks)
#pragma unroll
      for (int n = 0; n < 2; ++n)
#pragma unroll
        for (int m = 0; m < 4; ++m)
          acc[n][m] = __builtin_amdgcn_mfma_f32_16x16x32_bf16(
              wf[n][ks], xf[m][ks], acc[n][m], 0, 0, 0);
  };

  // ---- spline half: 36 steps, distance-2 ring, counted-vmcnt barriers ----
  bf16x8 wA[2][2], wB[2][2], wC[2][2];
  stageA(0, S0 + 0); loadB(wA, S0 + 0); // 6 VMEM ops
  stageA(1, S0 + 1); loadB(wB, S0 + 1); // 6 VMEM ops
  WAITBAR6();                           // step-0 landed; step-1 in flight

  for (int s = 0; s < NHALF - 3; s += 3) {
    stageA(2, S0 + s + 2); loadB(wC, S0 + s + 2);
    compute(0, wA);
    WAITBAR6();
    stageA(0, S0 + s + 3); loadB(wA, S0 + s + 3);
    compute(1, wB);
    WAITBAR6();
    stageA(1, S0 + s + 4); loadB(wB, S0 + s + 4);
    compute(2, wC);
    WAITBAR6();
  }
  // steps 33..35 of this half (33/buf0, 34/buf1 staged; stage 35 here)
  stageA(2, S0 + 35); loadB(wC, S0 + 35);
  compute(0, wA);                       // step 33
  WAITBAR6();                           // 34 landed; 35 in flight
  compute(1, wB);                       // step 34
  asm volatile("s_waitcnt vmcnt(0)" ::: "memory");
  __builtin_amdgcn_s_barrier();
  __builtin_amdgcn_sched_barrier(0);
  compute(2, wC);                       // step 35

  // ---- base phase (K-half 1 only): silu via LDS, 9 steps ----
  if (kh == 1) {
    const __bf16* seb = se + (size_t)b * SE_B + y0 * SE_YP;
    auto stageBase = [&](int buf, int j) {
      const int kt = j / 3, kw = j - 3 * kt;
      const int px = t & 127;
      const __bf16* src = seb + (kt + (px >> 6)) * SE_YP
                        + ((px & 63) + kw) * SE_XP;
#pragma unroll
      for (int h = 0; h < 2; ++h) {
        const int gslot = (t >> 7) * 2 + h;     // 0..7
        const int q     = gslot ^ (px & 7);     // channel-octet granule
        const bf16x8 v  = *(const bf16x8*)(src + q * 8);
        *(bf16x8*)(&As[buf][px][gslot * 8]) = v;
      }
    };

    stageBase(0, 0);                    // buf0 free (last compute used buf2)
    __syncthreads();
    bf16x8 wD[2][2];
    for (int bs = 0; bs < NBASE; ++bs) {
      const int cb = bs & 1;
      if (bs + 1 < NBASE) stageBase(cb ^ 1, bs + 1);
      loadB(wD, NSPL_STEPS + bs);
      compute(cb, wD);
      __syncthreads();
    }
  }

  // ---- epilogue: atomic-add partial D[co][pix] (bias pre-written) ----
#pragma unroll
  for (int n = 0; n < 2; ++n) {
    const int co = nq * 32 + n * 16 + g4 * 4;
#pragma unroll
    for (int m = 0; m < 4; ++m) {
      const int y = y0 + mh;
      const int xcoord = m * 16 + l15;
      float* o = out + (size_t)(b * C_OUT + co) * 4096 + y * 64 + xcoord;
#pragma unroll
      for (int i = 0; i < 4; ++i)
        unsafeAtomicAdd(o + (size_t)i * 4096, acc[n][m][i]);
    }
  }
}

extern "C" void kernel_launch(void* const* d_in, const int* in_sizes, int n_in,
                              void* d_out, int out_size, void* d_ws, size_t ws_size,
                              hipStream_t stream) {
  const float* x    = (const float*)d_in[0];
  const float* grid = (const float*)d_in[1];
  const float* sw   = (const float*)d_in[2];
  const float* bw   = (const float*)d_in[3];
  const float* bb   = (const float*)d_in[4];
  float* out = (float*)d_out;

  __bf16* wt3 = (__bf16*)d_ws;
  __bf16* xe  = (__bf16*)((char*)d_ws + XE_OFF);
  __bf16* se  = (__bf16*)((char*)d_ws + SE_OFF);

  prep_wt<<<NSTEPS, 256, 0, stream>>>(sw, bw, wt3);
  expand_xe<<<4224, 256, 0, stream>>>(x, grid, xe);
  expand_se<<<528, 256, 0, stream>>>(x, se);
  init_out<<<4096, 256, 0, stream>>>(bb, out);
  kan_gemm<<<512, 512, 0, stream>>>(xe, se, wt3, out);
}